// Round 15
// baseline (309.785 us; speedup 1.0000x reference)
//
#include <hip/hip_runtime.h>

// Problem constants
#define E_TOT 8192
#define NB    32
#define H     128
#define EPG   256          // edges per graph (contiguous slots)
#define NDT   34           // 32 edge-attr dims + 1 bias row + 1 root block
#define YD    33           // Y keeps only d<33 (root fused into h)
#define YCOLS (YD * H)     // 4224

// Stage-1 T-GEMM: K = 33*64 (msg+bias) + 64 (root) = 2176
#define KH1   2176
#define TROW1 (2 * KH1)    // [Th | Tl] = 4352 shorts/row
#define KSPLIT1 12         // 204 k-steps = 12 x 17

typedef __attribute__((ext_vector_type(8))) short bf16x8;
typedef __attribute__((ext_vector_type(4))) float f32x4;

__device__ __forceinline__ unsigned short bf16_rne(float f) {
    unsigned int u = __float_as_uint(f);
    unsigned int r = (u + 0x7FFFu + ((u >> 16) & 1u)) >> 16;
    return (unsigned short)r;
}
__device__ __forceinline__ float bf16_to_f32(unsigned short h) {
    return __uint_as_float(((unsigned int)h) << 16);
}

__device__ __forceinline__ void gload_lds16(const void* g, void* l) {
    __builtin_amdgcn_global_load_lds(
        (const __attribute__((address_space(1))) unsigned int*)g,
        (__attribute__((address_space(3))) unsigned int*)l, 16, 0, 0);
}

// ---------------------------------------------------------------------------
// prep_all: all input-side preprocessing in ONE dispatch (verified R5/R12).
//   [0,34): Bt1n units; [34,306): Bt2/Bt3 units; [306,562): t1 units.
// Block 0 zeroes the stats buffer. NO device barriers anywhere in this
// build: R13 measured a 256-block counter barrier at ~25-30us vs ~4.5us
// dispatch boundary — dispatch boundaries ARE the cheap grid-wide sync.
// ---------------------------------------------------------------------------
union PrepSMem {
    struct { unsigned short HI[128][72]; unsigned short LO[128][72]; } b1;
    struct { unsigned short HI[128][40]; unsigned short LO[128][40]; } bt;
    struct { float xL[128][64]; float eaL[256][32]; short srcL[256];
             short lists[16][256]; int cnt[16]; } t1;
};

__global__ __launch_bounds__(256)
void prep_all(const float* __restrict__ x, const float* __restrict__ ea,
              const int* __restrict__ esrc, const int* __restrict__ edst,
              const float* __restrict__ nn1w, const float* __restrict__ nn1b,
              const float* __restrict__ root1,
              const float* __restrict__ nn2w, const float* __restrict__ nn2b,
              const float* __restrict__ root2,
              const float* __restrict__ nn3w, const float* __restrict__ nn3b,
              const float* __restrict__ root3,
              unsigned short* __restrict__ Bt1, unsigned short* __restrict__ Bt2,
              unsigned short* __restrict__ Bt3, unsigned short* __restrict__ T1,
              float* __restrict__ stats)
{
    __shared__ PrepSMem sm;
    const int b   = blockIdx.x;
    const int tid = threadIdx.x;

    if (b < 34) {
        if (b == 0)
            for (int i = tid; i < 768; i += 256) stats[i] = 0.f;
        const int d = b;
        const float* __restrict__ W =
            (d < 32) ? (nn1w + (size_t)d * 8192) : ((d == 32) ? nn1b : root1);
        for (int idx = tid; idx < 64 * 128; idx += 256) {
            const int ii = idx >> 7, o = idx & 127;
            const float v = W[ii * 128 + o];
            const unsigned short h = bf16_rne(v);
            sm.b1.HI[o][ii] = h;
            sm.b1.LO[o][ii] = bf16_rne(v - bf16_to_f32(h));
        }
        __syncthreads();
        const int o = tid & 127, half = tid >> 7;
        const uint4* s4 = (const uint4*)(half ? &sm.b1.LO[o][0] : &sm.b1.HI[o][0]);
        uint4* d4 = (uint4*)(Bt1 + (size_t)o * TROW1 + (half ? KH1 : 0) + d * 64);
        #pragma unroll
        for (int q = 0; q < 8; ++q) d4[q] = s4[q];
    } else if (b < 306) {
        const int unit  = b - 34;
        const int stage = unit / 136;            // 0: stage2, 1: stage3
        const int u2    = unit - stage * 136;
        const int d  = u2 >> 2;
        const int i0 = (u2 & 3) * 32;
        const float* __restrict__ W = (stage == 0)
            ? ((d < 32) ? (nn2w + (size_t)d * 16384) : ((d == 32) ? nn2b : root2))
            : ((d < 32) ? (nn3w + (size_t)d * 16384) : ((d == 32) ? nn3b : root3));
        unsigned short* __restrict__ Bt = (stage == 0) ? Bt2 : Bt3;

        for (int idx = tid; idx < 32 * 128; idx += 256) {
            const int ii = idx >> 7, o = idx & 127;
            const float v = W[(size_t)(i0 + ii) * 128 + o];
            const unsigned short h = bf16_rne(v);
            sm.bt.HI[o][ii] = h;
            sm.bt.LO[o][ii] = bf16_rne(v - bf16_to_f32(h));
        }
        __syncthreads();
        const int o = tid & 127, half = tid >> 7;
        unsigned short* dst = Bt + (size_t)(d * 128 + o) * 384;
        const uint4* hs = (const uint4*)&sm.bt.HI[o][0];
        const uint4* ls = (const uint4*)&sm.bt.LO[o][0];
        if (half == 0) {
            uint4* p = (uint4*)(dst + i0);
            p[0] = hs[0]; p[1] = hs[1]; p[2] = hs[2]; p[3] = hs[3];
            uint4* q = (uint4*)(dst + 256 + i0);
            q[0] = ls[0]; q[1] = ls[1]; q[2] = ls[2]; q[3] = ls[3];
        } else {
            uint4* p = (uint4*)(dst + 128 + i0);
            p[0] = hs[0]; p[1] = hs[1]; p[2] = hs[2]; p[3] = hs[3];
        }
    } else {
        const int u    = b - 306;
        const int g    = u >> 3;
        const int base = (u & 7) * 16;
        const int wv   = tid >> 6;
        const int ln   = tid & 63;

        if (tid < 16) sm.t1.cnt[tid] = 0;
        for (int idx = tid; idx < 128 * 64; idx += 256)
            sm.t1.xL[idx >> 6][idx & 63] = x[(size_t)g * 8192 + idx];
        for (int idx = tid; idx < 256 * 32; idx += 256)
            sm.t1.eaL[idx >> 5][idx & 31] = ea[(size_t)g * 8192 + idx];
        __syncthreads();

        {
            const int e = tid;
            sm.t1.srcL[e] = (short)(esrc[g * EPG + e] - g * 128);
            const int r = (edst[g * EPG + e] - g * 128) - base;
            if (r >= 0 && r < 16) {
                const int pos = atomicAdd(&sm.t1.cnt[r], 1);
                sm.t1.lists[r][pos] = (short)e;
            }
        }
        __syncthreads();

        #pragma unroll
        for (int j = 0; j < 4; ++j) {
            const int r = wv * 4 + j;
            const int uu = base + r;
            float acc[33];
            #pragma unroll
            for (int d = 0; d < 33; ++d) acc[d] = 0.f;

            const int n = sm.t1.cnt[r];
            for (int t = 0; t < n; ++t) {
                const int e = sm.t1.lists[r][t];
                const float xv = sm.t1.xL[sm.t1.srcL[e]][ln];
                #pragma unroll
                for (int d = 0; d < 32; ++d) acc[d] += sm.t1.eaL[e][d] * xv;
                acc[32] += xv;
            }

            unsigned short* row = T1 + (size_t)(g * 128 + uu) * TROW1;
            #pragma unroll
            for (int d = 0; d < 33; ++d) {
                const unsigned short hb = bf16_rne(acc[d]);
                row[d * 64 + ln] = hb;
                row[KH1 + d * 64 + ln] = bf16_rne(acc[d] - bf16_to_f32(hb));
            }
            const float xv = sm.t1.xL[uu][ln];
            const unsigned short hb = bf16_rne(xv);
            row[2112 + ln] = hb;
            row[KH1 + 2112 + ln] = bf16_rne(xv - bf16_to_f32(hb));
        }
    }
}

// ---------------------------------------------------------------------------
// hgemm1: h1-partials = T1 @ Bt1n^T (verified R5). Grid (32, 12).
// ---------------------------------------------------------------------------
__global__ __launch_bounds__(256)
void hgemm1(const unsigned short* __restrict__ A,
            const unsigned short* __restrict__ Bt,
            const float* __restrict__ bias,
            float* __restrict__ hpart)
{
    __shared__ unsigned short Alds[128 * 32];
    __shared__ unsigned short Blds[128 * 32];

    const int lane = threadIdx.x & 63;
    const int w    = threadIdx.x >> 6;
    const int wm = w >> 1, wn = w & 1;
    const int v0 = blockIdx.x * 128;
    const int c  = blockIdx.y;

    f32x4 acc[4][4];
    #pragma unroll
    for (int i = 0; i < 4; ++i)
        #pragma unroll
        for (int j = 0; j < 4; ++j)
            acc[i][j] = (f32x4)(0.0f);

    const int arow = lane >> 2;
    const int acol = (lane & 3) * 8;
    const int koff = (lane >> 4) * 8;
    const int mrow = lane & 15;

    for (int t = c * 17; t < c * 17 + 17; ++t) {
        const int s  = t / 68;
        const int ko = (t - s * 68) * 32;
        const int aoff = (s == 2 ? KH1 : 0) + ko;
        const int boff = (s == 1 ? KH1 : 0) + ko;

        __syncthreads();
        #pragma unroll
        for (int tt = 0; tt < 2; ++tt) {
            const int cc = w * 2 + tt;
            const int r = cc * 16 + arow;
            gload_lds16(A  + (size_t)(v0 + r) * TROW1 + aoff + acol, &Alds[cc * 512]);
            gload_lds16(Bt + (size_t)r * TROW1 + boff + acol, &Blds[cc * 512]);
        }
        __syncthreads();

        bf16x8 a[4], b[4];
        #pragma unroll
        for (int f = 0; f < 4; ++f) {
            a[f] = *(const bf16x8*)&Alds[(wm * 64 + f * 16 + mrow) * 32 + koff];
            b[f] = *(const bf16x8*)&Blds[(wn * 64 + f * 16 + mrow) * 32 + koff];
        }
        #pragma unroll
        for (int fm = 0; fm < 4; ++fm)
            #pragma unroll
            for (int fn = 0; fn < 4; ++fn)
                acc[fm][fn] = __builtin_amdgcn_mfma_f32_16x16x32_bf16(
                    a[fm], b[fn], acc[fm][fn], 0, 0, 0);
    }

    float* out = hpart + (size_t)c * (4096 * 128);
    const int crow = (lane >> 4) * 4;
    const int ccol = lane & 15;
    #pragma unroll
    for (int fm = 0; fm < 4; ++fm) {
        const int gr = v0 + wm * 64 + fm * 16 + crow;
        #pragma unroll
        for (int fn = 0; fn < 4; ++fn) {
            const int col = wn * 64 + fn * 16 + ccol;
            const float bv = (c == 0) ? bias[col] : 0.f;
            #pragma unroll
            for (int r = 0; r < 4; ++r)
                out[(size_t)(gr + r) * H + col] = acc[fm][fn][r] + bv;
        }
    }
}

// ---------------------------------------------------------------------------
// hsum_stats: h1 = sum of 12 hpart slices (streaming, grid 512, verified
// R12/R14) + FUSED stage-1 column stats: per-thread (s, s^2) of its float4,
// LDS tree-reduce over the block's 8 rows, 256 atomics/block into stats.
// Saves the separate 2MB bn_stats pass + one dispatch boundary.
// Thread map: idx = blk*256+tid; row = idx>>5, col4 = tid&31, rg = tid>>5.
// ---------------------------------------------------------------------------
__global__ __launch_bounds__(256)
void hsum_stats(const float* __restrict__ hpart, float* __restrict__ h1,
                float* __restrict__ gsum, float* __restrict__ gsumsq)
{
    const int tid = threadIdx.x;
    const int idx = blockIdx.x * 256 + tid;    // [0, 131072)
    const float4* src = (const float4*)hpart;
    float4 v = src[idx];
    #pragma unroll
    for (int c = 1; c < KSPLIT1; ++c) {
        const float4 p = src[(size_t)c * (4096 * 32) + idx];
        v.x += p.x; v.y += p.y; v.z += p.z; v.w += p.w;
    }
    ((float4*)h1)[idx] = v;

    __shared__ float4 s4[256], q4[256];
    s4[tid] = v;
    q4[tid] = make_float4(v.x * v.x, v.y * v.y, v.z * v.z, v.w * v.w);
    __syncthreads();
    const int rg   = tid >> 5;                 // row-in-block 0..7
    const int col4 = tid & 31;                 // float4 column group
    #pragma unroll
    for (int off = 4; off > 0; off >>= 1) {
        if (rg < off) {
            float4 a = s4[tid], b = s4[tid + off * 32];
            a.x += b.x; a.y += b.y; a.z += b.z; a.w += b.w; s4[tid] = a;
            float4 c = q4[tid], d = q4[tid + off * 32];
            c.x += d.x; c.y += d.y; c.z += d.z; c.w += d.w; q4[tid] = c;
        }
        __syncthreads();
    }
    if (rg == 0) {
        const float4 ss = s4[col4], qq = q4[col4];
        atomicAdd(&gsum[col4 * 4 + 0], ss.x);
        atomicAdd(&gsum[col4 * 4 + 1], ss.y);
        atomicAdd(&gsum[col4 * 4 + 2], ss.z);
        atomicAdd(&gsum[col4 * 4 + 3], ss.w);
        atomicAdd(&gsumsq[col4 * 4 + 0], qq.x);
        atomicAdd(&gsumsq[col4 * 4 + 1], qq.y);
        atomicAdd(&gsumsq[col4 * 4 + 2], qq.z);
        atomicAdd(&gsumsq[col4 * 4 + 3], qq.w);
    }
}

// ---------------------------------------------------------------------------
// ygemm_mfma (stages 2,3 — verified R5)
// ---------------------------------------------------------------------------
template<int K3>
__global__ __launch_bounds__(256)
void ygemm_mfma(const unsigned short* __restrict__ A,
                const unsigned short* __restrict__ Bt,
                float* __restrict__ Y,
                const float* __restrict__ bias,
                float* __restrict__ h)
{
    __shared__ unsigned short Alds[128 * 32];
    __shared__ unsigned short Blds[128 * 32];

    const int lane = threadIdx.x & 63;
    const int w    = threadIdx.x >> 6;
    const int wm = w >> 1, wn = w & 1;
    const int v0 = blockIdx.x * 128;
    const int n0 = blockIdx.y * 128;

    f32x4 acc[4][4];
    #pragma unroll
    for (int i = 0; i < 4; ++i)
        #pragma unroll
        for (int j = 0; j < 4; ++j)
            acc[i][j] = (f32x4)(0.0f);

    const int arow = lane >> 2;
    const int acol = (lane & 3) * 8;
    const int koff = (lane >> 4) * 8;
    const int mrow = lane & 15;

    for (int k0 = 0; k0 < K3; k0 += 32) {
        __syncthreads();
        #pragma unroll
        for (int t = 0; t < 2; ++t) {
            const int c = w * 2 + t;
            const int r = c * 16 + arow;
            gload_lds16(A  + (size_t)(v0 + r) * K3 + k0 + acol, &Alds[c * 512]);
            gload_lds16(Bt + (size_t)(n0 + r) * K3 + k0 + acol, &Blds[c * 512]);
        }
        __syncthreads();

        bf16x8 a[4], b[4];
        #pragma unroll
        for (int f = 0; f < 4; ++f) {
            a[f] = *(const bf16x8*)&Alds[(wm * 64 + f * 16 + mrow) * 32 + koff];
            b[f] = *(const bf16x8*)&Blds[(wn * 64 + f * 16 + mrow) * 32 + koff];
        }
        #pragma unroll
        for (int fm = 0; fm < 4; ++fm)
            #pragma unroll
            for (int fn = 0; fn < 4; ++fn)
                acc[fm][fn] = __builtin_amdgcn_mfma_f32_16x16x32_bf16(
                    a[fm], b[fn], acc[fm][fn], 0, 0, 0);
    }

    const int crow = (lane >> 4) * 4;
    const int ccol = lane & 15;
    const bool is_root = (blockIdx.y == YD);
    #pragma unroll
    for (int fm = 0; fm < 4; ++fm) {
        const int gr = v0 + wm * 64 + fm * 16 + crow;
        #pragma unroll
        for (int fn = 0; fn < 4; ++fn) {
            const int col = wn * 64 + fn * 16 + ccol;
            if (is_root) {
                const float bv = bias[col];
                #pragma unroll
                for (int r = 0; r < 4; ++r)
                    h[(size_t)(gr + r) * H + col] = acc[fm][fn][r] + bv;
            } else {
                const size_t gc = (size_t)blockIdx.y * H + col;
                #pragma unroll
                for (int r = 0; r < 4; ++r)
                    Y[(size_t)(gr + r) * YCOLS + gc] = acc[fm][fn][r];
            }
        }
    }
}

// ---------------------------------------------------------------------------
// contract_edges: standalone 1024-block dispatch (verified R5).
// ---------------------------------------------------------------------------
__global__ __launch_bounds__(256)
void contract_edges(const float* __restrict__ Y,
                    const float* __restrict__ ea,
                    const int*   __restrict__ esrc,
                    const int*   __restrict__ edst,
                    float*       __restrict__ agg)
{
    const int grp = threadIdx.x >> 5;          // 8 groups per block
    const int l5  = threadIdx.x & 31;
    const int e   = blockIdx.x * 8 + grp;
    const int s   = esrc[e];
    if (s < 0) return;

    const float* yb  = Y + (size_t)s * YCOLS + l5 * 4;
    const float* ear = ea + (size_t)e * 32;

    float4 acc = *reinterpret_cast<const float4*>(yb + 32 * H);   // bias row, coef 1
    #pragma unroll 8
    for (int dd = 0; dd < 32; ++dd) {
        const float c = ear[dd];
        const float4 y = *reinterpret_cast<const float4*>(yb + dd * H);
        acc.x += c * y.x; acc.y += c * y.y; acc.z += c * y.z; acc.w += c * y.w;
    }
    float* out = agg + (size_t)edst[e] * H + l5 * 4;
    atomicAdd(out + 0, acc.x);
    atomicAdd(out + 1, acc.y);
    atomicAdd(out + 2, acc.z);
    atomicAdd(out + 3, acc.w);
}

// ---------------------------------------------------------------------------
// bn_stats_k: standalone column stats, grid 256 (verified R10/R14 scalar).
// ---------------------------------------------------------------------------
__global__ __launch_bounds__(256)
void bn_stats_k(const float* __restrict__ h, int n,
                float* __restrict__ gsum, float* __restrict__ gsumsq)
{
    __shared__ float sh[256];
    const int tid   = threadIdx.x;
    const int col   = tid & 127;
    const int rhalf = tid >> 7;
    float s = 0.f, sq = 0.f;
    for (int r = blockIdx.x * 2 + rhalf; r < n; r += 256 * 2) {
        float v = h[(size_t)r * H + col];
        s += v; sq += v * v;
    }
    sh[tid] = s;  __syncthreads();
    if (rhalf == 0) s += sh[tid + 128];
    __syncthreads();
    sh[tid] = sq; __syncthreads();
    if (rhalf == 0) {
        sq += sh[tid + 128];
        atomicAdd(&gsum[col], s);
        atomicAdd(&gsumsq[col], sq);
    }
}

// ---------------------------------------------------------------------------
// score_k: 8 blocks per graph (grid 256). Verified R13/R14.
// ---------------------------------------------------------------------------
__global__ __launch_bounds__(256)
void score_k(const float* __restrict__ h,
             const float* __restrict__ gsum, const float* __restrict__ gsumsq,
             float n_f,
             const float* __restrict__ gamma, const float* __restrict__ beta,
             const float* __restrict__ pw,
             int npg, float* __restrict__ scoreG)
{
    const int g   = blockIdx.x >> 3;
    const int sub = blockIdx.x & 7;
    const int tid = threadIdx.x;
    const int wv  = tid >> 6;
    const int ln  = tid & 63;

    __shared__ float muL[128], rsL[128], gmL[128], btL[128], pwL[128], red[128];
    __shared__ float sinv;

    if (tid < 128) {
        const float mu  = gsum[tid] / n_f;
        const float var = gsumsq[tid] / n_f - mu * mu;
        muL[tid] = mu;
        rsL[tid] = rsqrtf(var + 1e-5f);
        gmL[tid] = gamma[tid];
        btL[tid] = beta[tid];
        const float p = pw[tid];
        pwL[tid] = p;
        red[tid] = p * p;
    }
    __syncthreads();
    for (int off = 64; off > 0; off >>= 1) {
        if (tid < off) red[tid] += red[tid + off];
        __syncthreads();
    }
    if (tid == 0) sinv = rsqrtf(red[0]);
    __syncthreads();

    const int rps = npg >> 3;                   // rows per sub-block (16/8)
    for (int r = sub * rps + wv; r < (sub + 1) * rps; r += 4) {
        const float* hr = h + (size_t)(g * npg + r) * H;
        float p = 0.f;
        #pragma unroll
        for (int half = 0; half < 2; ++half) {
            const int c = ln + half * 64;
            const float y = fmaxf(gmL[c] * (hr[c] - muL[c]) * rsL[c] + btL[c], 0.f);
            p += y * pwL[c];
        }
        #pragma unroll
        for (int off = 32; off > 0; off >>= 1)
            p += __shfl_down(p, off, 64);
        if (ln == 0) scoreG[g * 128 + r] = tanhf(p * sinv);
    }
}

// ---------------------------------------------------------------------------
// emit_k: 8 blocks per graph (grid 256). Verified R13/R14.
// ---------------------------------------------------------------------------
__global__ __launch_bounds__(256)
void emit_k(const float* __restrict__ h,
            const float* __restrict__ gsum, const float* __restrict__ gsumsq,
            float n_f,
            const float* __restrict__ gamma, const float* __restrict__ beta,
            int npg, int k,
            const float* __restrict__ scoreG,
            const int* __restrict__ esrc_in, const int* __restrict__ edst_in,
            int* __restrict__ esrc_out, int* __restrict__ edst_out,
            unsigned short* __restrict__ Aout)
{
    const int g   = blockIdx.x >> 3;
    const int sub = blockIdx.x & 7;
    const int tid = threadIdx.x;
    const int wv  = tid >> 6;
    const int ln  = tid & 63;

    __shared__ float muL[128], rsL[128], gmL[128], btL[128];
    __shared__ float scoreL[128];
    __shared__ int   mapL[128];

    if (tid < 128) {
        const float mu  = gsum[tid] / n_f;
        const float var = gsumsq[tid] / n_f - mu * mu;
        muL[tid] = mu;
        rsL[tid] = rsqrtf(var + 1e-5f);
        gmL[tid] = gamma[tid];
        btL[tid] = beta[tid];
        if (tid < npg) scoreL[tid] = scoreG[g * 128 + tid];
    }
    __syncthreads();

    if (tid < npg) {
        const float si = scoreL[tid];
        int cnt = 0;
        for (int j = 0; j < npg; ++j) {
            const float sj = scoreL[j];
            cnt += (sj > si) || (sj == si && j < tid);
        }
        mapL[tid] = (cnt < k) ? cnt : -1;
    }
    __syncthreads();

    const int rps = npg >> 3;
    for (int r = sub * rps + wv; r < (sub + 1) * rps; r += 4) {
        const int nr = mapL[r];
        if (nr < 0) continue;
        const float sc = scoreL[r];
        const float* hr = h + (size_t)(g * npg + r) * H;
        unsigned short* arow = Aout + (size_t)(g * k + nr) * 384;
        #pragma unroll
        for (int half = 0; half < 2; ++half) {
            const int c = ln + half * 64;
            const float y = fmaxf(gmL[c] * (hr[c] - muL[c]) * rsL[c] + btL[c], 0.f) * sc;
            const unsigned short hb = bf16_rne(y);
            const unsigned short lb = bf16_rne(y - bf16_to_f32(hb));
            arow[c] = hb; arow[128 + c] = hb; arow[256 + c] = lb;
        }
    }

    if (tid < 32) {
        const int e = g * EPG + sub * 32 + tid;
        const int s = esrc_in[e];
        int ns = -1, nd = -1;
        if (s >= 0) {
            const int ms = mapL[s - g * npg];
            const int md = mapL[edst_in[e] - g * npg];
            if (ms >= 0 && md >= 0) { ns = g * k + ms; nd = g * k + md; }
        }
        esrc_out[e] = ns; edst_out[e] = nd;
    }
}

// ---------------------------------------------------------------------------
// fused_pool_final: stage-3 score + rank + mean-pool + MLP + sigmoid.
// 1 block/graph, grid 32 — R5-VERBATIM (verified; never appeared in any
// top-5: stage-3 npg=32 is small enough for the serial form).
// ---------------------------------------------------------------------------
__global__ __launch_bounds__(256)
void fused_pool_final(const float* __restrict__ h,
                      const float* __restrict__ gsum, const float* __restrict__ gsumsq,
                      float n_f,
                      const float* __restrict__ gamma, const float* __restrict__ beta,
                      const float* __restrict__ pw,
                      const float* __restrict__ lin1_w, const float* __restrict__ lin1_b,
                      const float* __restrict__ lin2_w, const float* __restrict__ lin2_b,
                      float* __restrict__ out)
{
    const int g   = blockIdx.x;
    const int tid = threadIdx.x;
    const int wv  = tid >> 6;
    const int ln  = tid & 63;
    const int npg = 32, k = 16;

    __shared__ float muL[128], rsL[128], gmL[128], btL[128], pwL[128];
    __shared__ float scoreL[32], red[128], gmean[128], h1c[64];
    __shared__ int   mapL[32];
    __shared__ float sinv;

    if (tid < 128) {
        const float mu  = gsum[tid] / n_f;
        const float var = gsumsq[tid] / n_f - mu * mu;
        muL[tid] = mu;
        rsL[tid] = rsqrtf(var + 1e-5f);
        gmL[tid] = gamma[tid];
        btL[tid] = beta[tid];
        const float p = pw[tid];
        pwL[tid] = p;
        red[tid] = p * p;
    }
    __syncthreads();
    for (int off = 64; off > 0; off >>= 1) {
        if (tid < off) red[tid] += red[tid + off];
        __syncthreads();
    }
    if (tid == 0) sinv = rsqrtf(red[0]);
    __syncthreads();

    for (int r = wv; r < npg; r += 4) {
        const float* hr = h + (size_t)(g * npg + r) * H;
        float p = 0.f;
        #pragma unroll
        for (int half = 0; half < 2; ++half) {
            const int c = ln + half * 64;
            const float y = fmaxf(gmL[c] * (hr[c] - muL[c]) * rsL[c] + btL[c], 0.f);
            p += y * pwL[c];
        }
        #pragma unroll
        for (int off = 32; off > 0; off >>= 1)
            p += __shfl_down(p, off, 64);
        if (ln == 0) scoreL[r] = tanhf(p * sinv);
    }
    __syncthreads();

    if (tid < npg) {
        const float si = scoreL[tid];
        int cnt = 0;
        for (int j = 0; j < npg; ++j) {
            const float sj = scoreL[j];
            cnt += (sj > si) || (sj == si && j < tid);
        }
        mapL[tid] = (cnt < k) ? cnt : -1;
    }
    __syncthreads();

    if (tid < 128) {
        float acc = 0.f;
        for (int r = 0; r < npg; ++r) {
            if (mapL[r] < 0) continue;
            const float hv = h[(size_t)(g * npg + r) * H + tid];
            const float y  = fmaxf(gmL[tid] * (hv - muL[tid]) * rsL[tid] + btL[tid], 0.f);
            acc += y * scoreL[r];
        }
        gmean[tid] = acc * (1.0f / 16.0f);
    }
    __syncthreads();

    if (tid < 64) {
        float acc = lin1_b[tid];
        for (int o = 0; o < 128; ++o) acc += gmean[o] * lin1_w[o * 64 + tid];
        h1c[tid] = fmaxf(acc, 0.f);
    }
    __syncthreads();
    if (tid == 0) {
        float z = lin2_b[0];
        for (int j = 0; j < 64; ++j) z += h1c[j] * lin2_w[j];
        out[g] = 1.0f / (1.0f + expf(-z));
    }
}

extern "C" void kernel_launch(void* const* d_in, const int* in_sizes, int n_in,
                              void* d_out, int out_size, void* d_ws, size_t ws_size,
                              hipStream_t stream)
{
    const float* x        = (const float*)d_in[0];
    const int*   ei       = (const int*)  d_in[1];
    const float* eattr    = (const float*)d_in[2];
    const float* nn1_w    = (const float*)d_in[4];
    const float* nn1_b    = (const float*)d_in[5];
    const float* root1    = (const float*)d_in[6];
    const float* bias1    = (const float*)d_in[7];
    const float* nn2_w    = (const float*)d_in[8];
    const float* nn2_b    = (const float*)d_in[9];
    const float* root2    = (const float*)d_in[10];
    const float* bias2    = (const float*)d_in[11];
    const float* nn3_w    = (const float*)d_in[12];
    const float* nn3_b    = (const float*)d_in[13];
    const float* root3    = (const float*)d_in[14];
    const float* bias3    = (const float*)d_in[15];
    const float* gamma1   = (const float*)d_in[16];
    const float* beta1    = (const float*)d_in[17];
    const float* gamma2   = (const float*)d_in[18];
    const float* beta2    = (const float*)d_in[19];
    const float* gamma3   = (const float*)d_in[20];
    const float* beta3    = (const float*)d_in[21];
    const float* pw1      = (const float*)d_in[22];
    const float* pw2      = (const float*)d_in[23];
    const float* pw3      = (const float*)d_in[24];
    const float* lin1_w   = (const float*)d_in[25];
    const float* lin1_b   = (const float*)d_in[26];
    const float* lin2_w   = (const float*)d_in[27];
    const float* lin2_b   = (const float*)d_in[28];

    const int* ei_src = ei;
    const int* ei_dst = ei + E_TOT;

    char* wp = (char*)d_ws;
    auto alloc = [&](size_t bytes) { char* p = wp; wp += (bytes + 255) & ~(size_t)255; return p; };
    float* h1   = (float*)alloc(4096 * 128 * 4);
    float* h2   = (float*)alloc(2048 * 128 * 4);
    float* h3   = (float*)alloc(1024 * 128 * 4);
    int*   src1 = (int*)alloc(E_TOT * 4);
    int*   dst1 = (int*)alloc(E_TOT * 4);
    int*   src2 = (int*)alloc(E_TOT * 4);
    int*   dst2 = (int*)alloc(E_TOT * 4);
    float* stats = (float*)alloc(6 * 128 * 4);
    float* scoreG = (float*)alloc(NB * 128 * 4);
    unsigned short* A2   = (unsigned short*)alloc((size_t)2048 * 384 * 2);
    unsigned short* A3   = (unsigned short*)alloc((size_t)1024 * 384 * 2);
    unsigned short* Bt1n = (unsigned short*)alloc((size_t)128 * TROW1 * 2);
    unsigned short* Bt2  = (unsigned short*)alloc((size_t)4352 * 384 * 2);
    unsigned short* Bt3  = (unsigned short*)alloc((size_t)4352 * 384 * 2);
    unsigned short* T1   = (unsigned short*)alloc((size_t)4096 * TROW1 * 2);  // 35.7 MB
    float* hpart = (float*)alloc((size_t)KSPLIT1 * 4096 * 128 * 4);           // 25 MB
    float* Ybuf  = (float*)alloc((size_t)2048 * YCOLS * 4);                   // 34.6 MB

    // 1. ALL preprocessing + stats zeroing
    prep_all<<<562, 256, 0, stream>>>(x, eattr, ei_src, ei_dst,
                                      nn1_w, nn1_b, root1,
                                      nn2_w, nn2_b, root2,
                                      nn3_w, nn3_b, root3,
                                      Bt1n, Bt2, Bt3, T1, stats);

    // 2-5. Stage 1: GEMM -> hsum+stats (fused) -> score -> emit
    hgemm1<<<dim3(32, KSPLIT1), 256, 0, stream>>>(T1, Bt1n, bias1, hpart);
    hsum_stats<<<512, 256, 0, stream>>>(hpart, h1, stats, stats + 128);
    score_k<<<256, 256, 0, stream>>>(h1, stats, stats + 128, 4096.0f,
                                     gamma1, beta1, pw1, 128, scoreG);
    emit_k<<<256, 256, 0, stream>>>(h1, stats, stats + 128, 4096.0f,
                                    gamma1, beta1, 128, 64, scoreG,
                                    ei_src, ei_dst, src1, dst1, A2);

    // 6-10. Stage 2
    ygemm_mfma<384><<<dim3(16, NDT), 256, 0, stream>>>(A2, Bt2, Ybuf, bias2, h2);
    contract_edges<<<E_TOT / 8, 256, 0, stream>>>(Ybuf, eattr, src1, dst1, h2);
    bn_stats_k<<<256, 256, 0, stream>>>(h2, 2048, stats + 256, stats + 384);
    score_k<<<256, 256, 0, stream>>>(h2, stats + 256, stats + 384, 2048.0f,
                                     gamma2, beta2, pw2, 64, scoreG);
    emit_k<<<256, 256, 0, stream>>>(h2, stats + 256, stats + 384, 2048.0f,
                                    gamma2, beta2, 64, 32, scoreG,
                                    src1, dst1, src2, dst2, A3);

    // 11-14. Stage 3
    ygemm_mfma<384><<<dim3(8, NDT), 256, 0, stream>>>(A3, Bt3, Ybuf, bias3, h3);
    contract_edges<<<E_TOT / 8, 256, 0, stream>>>(Ybuf, eattr, src2, dst2, h3);
    bn_stats_k<<<256, 256, 0, stream>>>(h3, 1024, stats + 512, stats + 640);
    fused_pool_final<<<NB, 256, 0, stream>>>(h3, stats + 512, stats + 640, 1024.0f,
                                             gamma3, beta3, pw3,
                                             lin1_w, lin1_b, lin2_w, lin2_b,
                                             (float*)d_out);
}

// Round 16
// 269.814 us; speedup vs baseline: 1.1481x; 1.1481x over previous
//
#include <hip/hip_runtime.h>

// Problem constants
#define E_TOT 8192
#define NB    32
#define H     128
#define EPG   256          // edges per graph (contiguous slots)
#define NDT   34           // 32 edge-attr dims + 1 bias row + 1 root block
#define YD    33           // Y keeps only d<33 (root fused into h)
#define YCOLS (YD * H)     // 4224

// Stage-1 T-GEMM: K = 33*64 (msg+bias) + 64 (root) = 2176
#define KH1   2176
#define TROW1 (2 * KH1)    // [Th | Tl] = 4352 shorts/row
#define KSPLIT1 12         // 204 k-steps = 12 x 17

typedef __attribute__((ext_vector_type(8))) short bf16x8;
typedef __attribute__((ext_vector_type(4))) float f32x4;

__device__ __forceinline__ unsigned short bf16_rne(float f) {
    unsigned int u = __float_as_uint(f);
    unsigned int r = (u + 0x7FFFu + ((u >> 16) & 1u)) >> 16;
    return (unsigned short)r;
}
__device__ __forceinline__ float bf16_to_f32(unsigned short h) {
    return __uint_as_float(((unsigned int)h) << 16);
}

__device__ __forceinline__ void gload_lds16(const void* g, void* l) {
    __builtin_amdgcn_global_load_lds(
        (const __attribute__((address_space(1))) unsigned int*)g,
        (__attribute__((address_space(3))) unsigned int*)l, 16, 0, 0);
}

// ---------------------------------------------------------------------------
// prep_all: all input-side preprocessing in ONE dispatch (verified R5/R12).
//   [0,34): Bt1n units; [34,306): Bt2/Bt3 units; [306,562): t1 units.
// Block 0 zeroes the stats buffer. NO device barriers in this build (R13:
// counter barrier ~25-30us vs ~4.5us dispatch boundary). NO fusion onto
// streaming kernels (R11/R15: sync+reduction grafts cost 3x their savings).
// ---------------------------------------------------------------------------
union PrepSMem {
    struct { unsigned short HI[128][72]; unsigned short LO[128][72]; } b1;
    struct { unsigned short HI[128][40]; unsigned short LO[128][40]; } bt;
    struct { float xL[128][64]; float eaL[256][32]; short srcL[256];
             short lists[16][256]; int cnt[16]; } t1;
};

__global__ __launch_bounds__(256)
void prep_all(const float* __restrict__ x, const float* __restrict__ ea,
              const int* __restrict__ esrc, const int* __restrict__ edst,
              const float* __restrict__ nn1w, const float* __restrict__ nn1b,
              const float* __restrict__ root1,
              const float* __restrict__ nn2w, const float* __restrict__ nn2b,
              const float* __restrict__ root2,
              const float* __restrict__ nn3w, const float* __restrict__ nn3b,
              const float* __restrict__ root3,
              unsigned short* __restrict__ Bt1, unsigned short* __restrict__ Bt2,
              unsigned short* __restrict__ Bt3, unsigned short* __restrict__ T1,
              float* __restrict__ stats)
{
    __shared__ PrepSMem sm;
    const int b   = blockIdx.x;
    const int tid = threadIdx.x;

    if (b < 34) {
        if (b == 0)
            for (int i = tid; i < 768; i += 256) stats[i] = 0.f;
        const int d = b;
        const float* __restrict__ W =
            (d < 32) ? (nn1w + (size_t)d * 8192) : ((d == 32) ? nn1b : root1);
        for (int idx = tid; idx < 64 * 128; idx += 256) {
            const int ii = idx >> 7, o = idx & 127;
            const float v = W[ii * 128 + o];
            const unsigned short h = bf16_rne(v);
            sm.b1.HI[o][ii] = h;
            sm.b1.LO[o][ii] = bf16_rne(v - bf16_to_f32(h));
        }
        __syncthreads();
        const int o = tid & 127, half = tid >> 7;
        const uint4* s4 = (const uint4*)(half ? &sm.b1.LO[o][0] : &sm.b1.HI[o][0]);
        uint4* d4 = (uint4*)(Bt1 + (size_t)o * TROW1 + (half ? KH1 : 0) + d * 64);
        #pragma unroll
        for (int q = 0; q < 8; ++q) d4[q] = s4[q];
    } else if (b < 306) {
        const int unit  = b - 34;
        const int stage = unit / 136;            // 0: stage2, 1: stage3
        const int u2    = unit - stage * 136;
        const int d  = u2 >> 2;
        const int i0 = (u2 & 3) * 32;
        const float* __restrict__ W = (stage == 0)
            ? ((d < 32) ? (nn2w + (size_t)d * 16384) : ((d == 32) ? nn2b : root2))
            : ((d < 32) ? (nn3w + (size_t)d * 16384) : ((d == 32) ? nn3b : root3));
        unsigned short* __restrict__ Bt = (stage == 0) ? Bt2 : Bt3;

        for (int idx = tid; idx < 32 * 128; idx += 256) {
            const int ii = idx >> 7, o = idx & 127;
            const float v = W[(size_t)(i0 + ii) * 128 + o];
            const unsigned short h = bf16_rne(v);
            sm.bt.HI[o][ii] = h;
            sm.bt.LO[o][ii] = bf16_rne(v - bf16_to_f32(h));
        }
        __syncthreads();
        const int o = tid & 127, half = tid >> 7;
        unsigned short* dst = Bt + (size_t)(d * 128 + o) * 384;
        const uint4* hs = (const uint4*)&sm.bt.HI[o][0];
        const uint4* ls = (const uint4*)&sm.bt.LO[o][0];
        if (half == 0) {
            uint4* p = (uint4*)(dst + i0);
            p[0] = hs[0]; p[1] = hs[1]; p[2] = hs[2]; p[3] = hs[3];
            uint4* q = (uint4*)(dst + 256 + i0);
            q[0] = ls[0]; q[1] = ls[1]; q[2] = ls[2]; q[3] = ls[3];
        } else {
            uint4* p = (uint4*)(dst + 128 + i0);
            p[0] = hs[0]; p[1] = hs[1]; p[2] = hs[2]; p[3] = hs[3];
        }
    } else {
        const int u    = b - 306;
        const int g    = u >> 3;
        const int base = (u & 7) * 16;
        const int wv   = tid >> 6;
        const int ln   = tid & 63;

        if (tid < 16) sm.t1.cnt[tid] = 0;
        for (int idx = tid; idx < 128 * 64; idx += 256)
            sm.t1.xL[idx >> 6][idx & 63] = x[(size_t)g * 8192 + idx];
        for (int idx = tid; idx < 256 * 32; idx += 256)
            sm.t1.eaL[idx >> 5][idx & 31] = ea[(size_t)g * 8192 + idx];
        __syncthreads();

        {
            const int e = tid;
            sm.t1.srcL[e] = (short)(esrc[g * EPG + e] - g * 128);
            const int r = (edst[g * EPG + e] - g * 128) - base;
            if (r >= 0 && r < 16) {
                const int pos = atomicAdd(&sm.t1.cnt[r], 1);
                sm.t1.lists[r][pos] = (short)e;
            }
        }
        __syncthreads();

        #pragma unroll
        for (int j = 0; j < 4; ++j) {
            const int r = wv * 4 + j;
            const int uu = base + r;
            float acc[33];
            #pragma unroll
            for (int d = 0; d < 33; ++d) acc[d] = 0.f;

            const int n = sm.t1.cnt[r];
            for (int t = 0; t < n; ++t) {
                const int e = sm.t1.lists[r][t];
                const float xv = sm.t1.xL[sm.t1.srcL[e]][ln];
                #pragma unroll
                for (int d = 0; d < 32; ++d) acc[d] += sm.t1.eaL[e][d] * xv;
                acc[32] += xv;
            }

            unsigned short* row = T1 + (size_t)(g * 128 + uu) * TROW1;
            #pragma unroll
            for (int d = 0; d < 33; ++d) {
                const unsigned short hb = bf16_rne(acc[d]);
                row[d * 64 + ln] = hb;
                row[KH1 + d * 64 + ln] = bf16_rne(acc[d] - bf16_to_f32(hb));
            }
            const float xv = sm.t1.xL[uu][ln];
            const unsigned short hb = bf16_rne(xv);
            row[2112 + ln] = hb;
            row[KH1 + 2112 + ln] = bf16_rne(xv - bf16_to_f32(hb));
        }
    }
}

// ---------------------------------------------------------------------------
// hgemm1: h1-partials = T1 @ Bt1n^T (verified R5). Grid (32, 12).
// ---------------------------------------------------------------------------
__global__ __launch_bounds__(256)
void hgemm1(const unsigned short* __restrict__ A,
            const unsigned short* __restrict__ Bt,
            const float* __restrict__ bias,
            float* __restrict__ hpart)
{
    __shared__ unsigned short Alds[128 * 32];
    __shared__ unsigned short Blds[128 * 32];

    const int lane = threadIdx.x & 63;
    const int w    = threadIdx.x >> 6;
    const int wm = w >> 1, wn = w & 1;
    const int v0 = blockIdx.x * 128;
    const int c  = blockIdx.y;

    f32x4 acc[4][4];
    #pragma unroll
    for (int i = 0; i < 4; ++i)
        #pragma unroll
        for (int j = 0; j < 4; ++j)
            acc[i][j] = (f32x4)(0.0f);

    const int arow = lane >> 2;
    const int acol = (lane & 3) * 8;
    const int koff = (lane >> 4) * 8;
    const int mrow = lane & 15;

    for (int t = c * 17; t < c * 17 + 17; ++t) {
        const int s  = t / 68;
        const int ko = (t - s * 68) * 32;
        const int aoff = (s == 2 ? KH1 : 0) + ko;
        const int boff = (s == 1 ? KH1 : 0) + ko;

        __syncthreads();
        #pragma unroll
        for (int tt = 0; tt < 2; ++tt) {
            const int cc = w * 2 + tt;
            const int r = cc * 16 + arow;
            gload_lds16(A  + (size_t)(v0 + r) * TROW1 + aoff + acol, &Alds[cc * 512]);
            gload_lds16(Bt + (size_t)r * TROW1 + boff + acol, &Blds[cc * 512]);
        }
        __syncthreads();

        bf16x8 a[4], b[4];
        #pragma unroll
        for (int f = 0; f < 4; ++f) {
            a[f] = *(const bf16x8*)&Alds[(wm * 64 + f * 16 + mrow) * 32 + koff];
            b[f] = *(const bf16x8*)&Blds[(wn * 64 + f * 16 + mrow) * 32 + koff];
        }
        #pragma unroll
        for (int fm = 0; fm < 4; ++fm)
            #pragma unroll
            for (int fn = 0; fn < 4; ++fn)
                acc[fm][fn] = __builtin_amdgcn_mfma_f32_16x16x32_bf16(
                    a[fm], b[fn], acc[fm][fn], 0, 0, 0);
    }

    float* out = hpart + (size_t)c * (4096 * 128);
    const int crow = (lane >> 4) * 4;
    const int ccol = lane & 15;
    #pragma unroll
    for (int fm = 0; fm < 4; ++fm) {
        const int gr = v0 + wm * 64 + fm * 16 + crow;
        #pragma unroll
        for (int fn = 0; fn < 4; ++fn) {
            const int col = wn * 64 + fn * 16 + ccol;
            const float bv = (c == 0) ? bias[col] : 0.f;
            #pragma unroll
            for (int r = 0; r < 4; ++r)
                out[(size_t)(gr + r) * H + col] = acc[fm][fn][r] + bv;
        }
    }
}

// ---------------------------------------------------------------------------
// hsum: h1 = sum of 12 hpart slices. PURE streaming, no atomics, no syncs,
// grid 512 (verified R12/R14). R15 lesson: do NOT fuse stats in here.
// ---------------------------------------------------------------------------
__global__ __launch_bounds__(256)
void hsum(const float* __restrict__ hpart, float* __restrict__ h1)
{
    const int idx = blockIdx.x * 256 + threadIdx.x;    // [0, 131072)
    const float4* src = (const float4*)hpart;
    float4 v = src[idx];
    #pragma unroll
    for (int c = 1; c < KSPLIT1; ++c) {
        const float4 p = src[(size_t)c * (4096 * 32) + idx];
        v.x += p.x; v.y += p.y; v.z += p.z; v.w += p.w;
    }
    ((float4*)h1)[idx] = v;
}

// ---------------------------------------------------------------------------
// ygemm_mfma (stages 2,3 — verified R5)
// ---------------------------------------------------------------------------
template<int K3>
__global__ __launch_bounds__(256)
void ygemm_mfma(const unsigned short* __restrict__ A,
                const unsigned short* __restrict__ Bt,
                float* __restrict__ Y,
                const float* __restrict__ bias,
                float* __restrict__ h)
{
    __shared__ unsigned short Alds[128 * 32];
    __shared__ unsigned short Blds[128 * 32];

    const int lane = threadIdx.x & 63;
    const int w    = threadIdx.x >> 6;
    const int wm = w >> 1, wn = w & 1;
    const int v0 = blockIdx.x * 128;
    const int n0 = blockIdx.y * 128;

    f32x4 acc[4][4];
    #pragma unroll
    for (int i = 0; i < 4; ++i)
        #pragma unroll
        for (int j = 0; j < 4; ++j)
            acc[i][j] = (f32x4)(0.0f);

    const int arow = lane >> 2;
    const int acol = (lane & 3) * 8;
    const int koff = (lane >> 4) * 8;
    const int mrow = lane & 15;

    for (int k0 = 0; k0 < K3; k0 += 32) {
        __syncthreads();
        #pragma unroll
        for (int t = 0; t < 2; ++t) {
            const int c = w * 2 + t;
            const int r = c * 16 + arow;
            gload_lds16(A  + (size_t)(v0 + r) * K3 + k0 + acol, &Alds[c * 512]);
            gload_lds16(Bt + (size_t)(n0 + r) * K3 + k0 + acol, &Blds[c * 512]);
        }
        __syncthreads();

        bf16x8 a[4], b[4];
        #pragma unroll
        for (int f = 0; f < 4; ++f) {
            a[f] = *(const bf16x8*)&Alds[(wm * 64 + f * 16 + mrow) * 32 + koff];
            b[f] = *(const bf16x8*)&Blds[(wn * 64 + f * 16 + mrow) * 32 + koff];
        }
        #pragma unroll
        for (int fm = 0; fm < 4; ++fm)
            #pragma unroll
            for (int fn = 0; fn < 4; ++fn)
                acc[fm][fn] = __builtin_amdgcn_mfma_f32_16x16x32_bf16(
                    a[fm], b[fn], acc[fm][fn], 0, 0, 0);
    }

    const int crow = (lane >> 4) * 4;
    const int ccol = lane & 15;
    const bool is_root = (blockIdx.y == YD);
    #pragma unroll
    for (int fm = 0; fm < 4; ++fm) {
        const int gr = v0 + wm * 64 + fm * 16 + crow;
        #pragma unroll
        for (int fn = 0; fn < 4; ++fn) {
            const int col = wn * 64 + fn * 16 + ccol;
            if (is_root) {
                const float bv = bias[col];
                #pragma unroll
                for (int r = 0; r < 4; ++r)
                    h[(size_t)(gr + r) * H + col] = acc[fm][fn][r] + bv;
            } else {
                const size_t gc = (size_t)blockIdx.y * H + col;
                #pragma unroll
                for (int r = 0; r < 4; ++r)
                    Y[(size_t)(gr + r) * YCOLS + gc] = acc[fm][fn][r];
            }
        }
    }
}

// ---------------------------------------------------------------------------
// contract_edges: standalone 1024-block dispatch (verified R5).
// ---------------------------------------------------------------------------
__global__ __launch_bounds__(256)
void contract_edges(const float* __restrict__ Y,
                    const float* __restrict__ ea,
                    const int*   __restrict__ esrc,
                    const int*   __restrict__ edst,
                    float*       __restrict__ agg)
{
    const int grp = threadIdx.x >> 5;          // 8 groups per block
    const int l5  = threadIdx.x & 31;
    const int e   = blockIdx.x * 8 + grp;
    const int s   = esrc[e];
    if (s < 0) return;

    const float* yb  = Y + (size_t)s * YCOLS + l5 * 4;
    const float* ear = ea + (size_t)e * 32;

    float4 acc = *reinterpret_cast<const float4*>(yb + 32 * H);   // bias row, coef 1
    #pragma unroll 8
    for (int dd = 0; dd < 32; ++dd) {
        const float c = ear[dd];
        const float4 y = *reinterpret_cast<const float4*>(yb + dd * H);
        acc.x += c * y.x; acc.y += c * y.y; acc.z += c * y.z; acc.w += c * y.w;
    }
    float* out = agg + (size_t)edst[e] * H + l5 * 4;
    atomicAdd(out + 0, acc.x);
    atomicAdd(out + 1, acc.y);
    atomicAdd(out + 2, acc.z);
    atomicAdd(out + 3, acc.w);
}

// ---------------------------------------------------------------------------
// bn_stats_k: standalone column stats, grid 256 (verified R10/R14 scalar).
// ---------------------------------------------------------------------------
__global__ __launch_bounds__(256)
void bn_stats_k(const float* __restrict__ h, int n,
                float* __restrict__ gsum, float* __restrict__ gsumsq)
{
    __shared__ float sh[256];
    const int tid   = threadIdx.x;
    const int col   = tid & 127;
    const int rhalf = tid >> 7;
    float s = 0.f, sq = 0.f;
    for (int r = blockIdx.x * 2 + rhalf; r < n; r += 256 * 2) {
        float v = h[(size_t)r * H + col];
        s += v; sq += v * v;
    }
    sh[tid] = s;  __syncthreads();
    if (rhalf == 0) s += sh[tid + 128];
    __syncthreads();
    sh[tid] = sq; __syncthreads();
    if (rhalf == 0) {
        sq += sh[tid + 128];
        atomicAdd(&gsum[col], s);
        atomicAdd(&gsumsq[col], sq);
    }
}

// ---------------------------------------------------------------------------
// score_k: 8 blocks per graph (grid 256). Verified R13/R14.
// ---------------------------------------------------------------------------
__global__ __launch_bounds__(256)
void score_k(const float* __restrict__ h,
             const float* __restrict__ gsum, const float* __restrict__ gsumsq,
             float n_f,
             const float* __restrict__ gamma, const float* __restrict__ beta,
             const float* __restrict__ pw,
             int npg, float* __restrict__ scoreG)
{
    const int g   = blockIdx.x >> 3;
    const int sub = blockIdx.x & 7;
    const int tid = threadIdx.x;
    const int wv  = tid >> 6;
    const int ln  = tid & 63;

    __shared__ float muL[128], rsL[128], gmL[128], btL[128], pwL[128], red[128];
    __shared__ float sinv;

    if (tid < 128) {
        const float mu  = gsum[tid] / n_f;
        const float var = gsumsq[tid] / n_f - mu * mu;
        muL[tid] = mu;
        rsL[tid] = rsqrtf(var + 1e-5f);
        gmL[tid] = gamma[tid];
        btL[tid] = beta[tid];
        const float p = pw[tid];
        pwL[tid] = p;
        red[tid] = p * p;
    }
    __syncthreads();
    for (int off = 64; off > 0; off >>= 1) {
        if (tid < off) red[tid] += red[tid + off];
        __syncthreads();
    }
    if (tid == 0) sinv = rsqrtf(red[0]);
    __syncthreads();

    const int rps = npg >> 3;                   // rows per sub-block (16/8)
    for (int r = sub * rps + wv; r < (sub + 1) * rps; r += 4) {
        const float* hr = h + (size_t)(g * npg + r) * H;
        float p = 0.f;
        #pragma unroll
        for (int half = 0; half < 2; ++half) {
            const int c = ln + half * 64;
            const float y = fmaxf(gmL[c] * (hr[c] - muL[c]) * rsL[c] + btL[c], 0.f);
            p += y * pwL[c];
        }
        #pragma unroll
        for (int off = 32; off > 0; off >>= 1)
            p += __shfl_down(p, off, 64);
        if (ln == 0) scoreG[g * 128 + r] = tanhf(p * sinv);
    }
}

// ---------------------------------------------------------------------------
// emit_k: 8 blocks per graph (grid 256). Verified R13/R14.
// ---------------------------------------------------------------------------
__global__ __launch_bounds__(256)
void emit_k(const float* __restrict__ h,
            const float* __restrict__ gsum, const float* __restrict__ gsumsq,
            float n_f,
            const float* __restrict__ gamma, const float* __restrict__ beta,
            int npg, int k,
            const float* __restrict__ scoreG,
            const int* __restrict__ esrc_in, const int* __restrict__ edst_in,
            int* __restrict__ esrc_out, int* __restrict__ edst_out,
            unsigned short* __restrict__ Aout)
{
    const int g   = blockIdx.x >> 3;
    const int sub = blockIdx.x & 7;
    const int tid = threadIdx.x;
    const int wv  = tid >> 6;
    const int ln  = tid & 63;

    __shared__ float muL[128], rsL[128], gmL[128], btL[128];
    __shared__ float scoreL[128];
    __shared__ int   mapL[128];

    if (tid < 128) {
        const float mu  = gsum[tid] / n_f;
        const float var = gsumsq[tid] / n_f - mu * mu;
        muL[tid] = mu;
        rsL[tid] = rsqrtf(var + 1e-5f);
        gmL[tid] = gamma[tid];
        btL[tid] = beta[tid];
        if (tid < npg) scoreL[tid] = scoreG[g * 128 + tid];
    }
    __syncthreads();

    if (tid < npg) {
        const float si = scoreL[tid];
        int cnt = 0;
        for (int j = 0; j < npg; ++j) {
            const float sj = scoreL[j];
            cnt += (sj > si) || (sj == si && j < tid);
        }
        mapL[tid] = (cnt < k) ? cnt : -1;
    }
    __syncthreads();

    const int rps = npg >> 3;
    for (int r = sub * rps + wv; r < (sub + 1) * rps; r += 4) {
        const int nr = mapL[r];
        if (nr < 0) continue;
        const float sc = scoreL[r];
        const float* hr = h + (size_t)(g * npg + r) * H;
        unsigned short* arow = Aout + (size_t)(g * k + nr) * 384;
        #pragma unroll
        for (int half = 0; half < 2; ++half) {
            const int c = ln + half * 64;
            const float y = fmaxf(gmL[c] * (hr[c] - muL[c]) * rsL[c] + btL[c], 0.f) * sc;
            const unsigned short hb = bf16_rne(y);
            const unsigned short lb = bf16_rne(y - bf16_to_f32(hb));
            arow[c] = hb; arow[128 + c] = hb; arow[256 + c] = lb;
        }
    }

    if (tid < 32) {
        const int e = g * EPG + sub * 32 + tid;
        const int s = esrc_in[e];
        int ns = -1, nd = -1;
        if (s >= 0) {
            const int ms = mapL[s - g * npg];
            const int md = mapL[edst_in[e] - g * npg];
            if (ms >= 0 && md >= 0) { ns = g * k + ms; nd = g * k + md; }
        }
        esrc_out[e] = ns; edst_out[e] = nd;
    }
}

// ---------------------------------------------------------------------------
// fused_pool_final: stage-3 score + rank + mean-pool + MLP + sigmoid.
// 1 block/graph, grid 32 — R5-VERBATIM (verified; never in any top-5).
// Replaces {score_k, final_tail_k}: -1 dispatch boundary.
// ---------------------------------------------------------------------------
__global__ __launch_bounds__(256)
void fused_pool_final(const float* __restrict__ h,
                      const float* __restrict__ gsum, const float* __restrict__ gsumsq,
                      float n_f,
                      const float* __restrict__ gamma, const float* __restrict__ beta,
                      const float* __restrict__ pw,
                      const float* __restrict__ lin1_w, const float* __restrict__ lin1_b,
                      const float* __restrict__ lin2_w, const float* __restrict__ lin2_b,
                      float* __restrict__ out)
{
    const int g   = blockIdx.x;
    const int tid = threadIdx.x;
    const int wv  = tid >> 6;
    const int ln  = tid & 63;
    const int npg = 32, k = 16;

    __shared__ float muL[128], rsL[128], gmL[128], btL[128], pwL[128];
    __shared__ float scoreL[32], red[128], gmean[128], h1c[64];
    __shared__ int   mapL[32];
    __shared__ float sinv;

    if (tid < 128) {
        const float mu  = gsum[tid] / n_f;
        const float var = gsumsq[tid] / n_f - mu * mu;
        muL[tid] = mu;
        rsL[tid] = rsqrtf(var + 1e-5f);
        gmL[tid] = gamma[tid];
        btL[tid] = beta[tid];
        const float p = pw[tid];
        pwL[tid] = p;
        red[tid] = p * p;
    }
    __syncthreads();
    for (int off = 64; off > 0; off >>= 1) {
        if (tid < off) red[tid] += red[tid + off];
        __syncthreads();
    }
    if (tid == 0) sinv = rsqrtf(red[0]);
    __syncthreads();

    for (int r = wv; r < npg; r += 4) {
        const float* hr = h + (size_t)(g * npg + r) * H;
        float p = 0.f;
        #pragma unroll
        for (int half = 0; half < 2; ++half) {
            const int c = ln + half * 64;
            const float y = fmaxf(gmL[c] * (hr[c] - muL[c]) * rsL[c] + btL[c], 0.f);
            p += y * pwL[c];
        }
        #pragma unroll
        for (int off = 32; off > 0; off >>= 1)
            p += __shfl_down(p, off, 64);
        if (ln == 0) scoreL[r] = tanhf(p * sinv);
    }
    __syncthreads();

    if (tid < npg) {
        const float si = scoreL[tid];
        int cnt = 0;
        for (int j = 0; j < npg; ++j) {
            const float sj = scoreL[j];
            cnt += (sj > si) || (sj == si && j < tid);
        }
        mapL[tid] = (cnt < k) ? cnt : -1;
    }
    __syncthreads();

    if (tid < 128) {
        float acc = 0.f;
        for (int r = 0; r < npg; ++r) {
            if (mapL[r] < 0) continue;
            const float hv = h[(size_t)(g * npg + r) * H + tid];
            const float y  = fmaxf(gmL[tid] * (hv - muL[tid]) * rsL[tid] + btL[tid], 0.f);
            acc += y * scoreL[r];
        }
        gmean[tid] = acc * (1.0f / 16.0f);
    }
    __syncthreads();

    if (tid < 64) {
        float acc = lin1_b[tid];
        for (int o = 0; o < 128; ++o) acc += gmean[o] * lin1_w[o * 64 + tid];
        h1c[tid] = fmaxf(acc, 0.f);
    }
    __syncthreads();
    if (tid == 0) {
        float z = lin2_b[0];
        for (int j = 0; j < 64; ++j) z += h1c[j] * lin2_w[j];
        out[g] = 1.0f / (1.0f + expf(-z));
    }
}

extern "C" void kernel_launch(void* const* d_in, const int* in_sizes, int n_in,
                              void* d_out, int out_size, void* d_ws, size_t ws_size,
                              hipStream_t stream)
{
    const float* x        = (const float*)d_in[0];
    const int*   ei       = (const int*)  d_in[1];
    const float* eattr    = (const float*)d_in[2];
    const float* nn1_w    = (const float*)d_in[4];
    const float* nn1_b    = (const float*)d_in[5];
    const float* root1    = (const float*)d_in[6];
    const float* bias1    = (const float*)d_in[7];
    const float* nn2_w    = (const float*)d_in[8];
    const float* nn2_b    = (const float*)d_in[9];
    const float* root2    = (const float*)d_in[10];
    const float* bias2    = (const float*)d_in[11];
    const float* nn3_w    = (const float*)d_in[12];
    const float* nn3_b    = (const float*)d_in[13];
    const float* root3    = (const float*)d_in[14];
    const float* bias3    = (const float*)d_in[15];
    const float* gamma1   = (const float*)d_in[16];
    const float* beta1    = (const float*)d_in[17];
    const float* gamma2   = (const float*)d_in[18];
    const float* beta2    = (const float*)d_in[19];
    const float* gamma3   = (const float*)d_in[20];
    const float* beta3    = (const float*)d_in[21];
    const float* pw1      = (const float*)d_in[22];
    const float* pw2      = (const float*)d_in[23];
    const float* pw3      = (const float*)d_in[24];
    const float* lin1_w   = (const float*)d_in[25];
    const float* lin1_b   = (const float*)d_in[26];
    const float* lin2_w   = (const float*)d_in[27];
    const float* lin2_b   = (const float*)d_in[28];

    const int* ei_src = ei;
    const int* ei_dst = ei + E_TOT;

    char* wp = (char*)d_ws;
    auto alloc = [&](size_t bytes) { char* p = wp; wp += (bytes + 255) & ~(size_t)255; return p; };
    float* h1   = (float*)alloc(4096 * 128 * 4);
    float* h2   = (float*)alloc(2048 * 128 * 4);
    float* h3   = (float*)alloc(1024 * 128 * 4);
    int*   src1 = (int*)alloc(E_TOT * 4);
    int*   dst1 = (int*)alloc(E_TOT * 4);
    int*   src2 = (int*)alloc(E_TOT * 4);
    int*   dst2 = (int*)alloc(E_TOT * 4);
    float* stats = (float*)alloc(6 * 128 * 4);
    float* scoreG = (float*)alloc(NB * 128 * 4);
    unsigned short* A2   = (unsigned short*)alloc((size_t)2048 * 384 * 2);
    unsigned short* A3   = (unsigned short*)alloc((size_t)1024 * 384 * 2);
    unsigned short* Bt1n = (unsigned short*)alloc((size_t)128 * TROW1 * 2);
    unsigned short* Bt2  = (unsigned short*)alloc((size_t)4352 * 384 * 2);
    unsigned short* Bt3  = (unsigned short*)alloc((size_t)4352 * 384 * 2);
    unsigned short* T1   = (unsigned short*)alloc((size_t)4096 * TROW1 * 2);  // 35.7 MB
    float* hpart = (float*)alloc((size_t)KSPLIT1 * 4096 * 128 * 4);           // 25 MB
    float* Ybuf  = (float*)alloc((size_t)2048 * YCOLS * 4);                   // 34.6 MB

    // 1. ALL preprocessing + stats zeroing
    prep_all<<<562, 256, 0, stream>>>(x, eattr, ei_src, ei_dst,
                                      nn1_w, nn1_b, root1,
                                      nn2_w, nn2_b, root2,
                                      nn3_w, nn3_b, root3,
                                      Bt1n, Bt2, Bt3, T1, stats);

    // 2-6. Stage 1: GEMM -> hsum -> stats -> score -> emit
    hgemm1<<<dim3(32, KSPLIT1), 256, 0, stream>>>(T1, Bt1n, bias1, hpart);
    hsum<<<512, 256, 0, stream>>>(hpart, h1);
    bn_stats_k<<<256, 256, 0, stream>>>(h1, 4096, stats, stats + 128);
    score_k<<<256, 256, 0, stream>>>(h1, stats, stats + 128, 4096.0f,
                                     gamma1, beta1, pw1, 128, scoreG);
    emit_k<<<256, 256, 0, stream>>>(h1, stats, stats + 128, 4096.0f,
                                    gamma1, beta1, 128, 64, scoreG,
                                    ei_src, ei_dst, src1, dst1, A2);

    // 7-11. Stage 2
    ygemm_mfma<384><<<dim3(16, NDT), 256, 0, stream>>>(A2, Bt2, Ybuf, bias2, h2);
    contract_edges<<<E_TOT / 8, 256, 0, stream>>>(Ybuf, eattr, src1, dst1, h2);
    bn_stats_k<<<256, 256, 0, stream>>>(h2, 2048, stats + 256, stats + 384);
    score_k<<<256, 256, 0, stream>>>(h2, stats + 256, stats + 384, 2048.0f,
                                     gamma2, beta2, pw2, 64, scoreG);
    emit_k<<<256, 256, 0, stream>>>(h2, stats + 256, stats + 384, 2048.0f,
                                    gamma2, beta2, 64, 32, scoreG,
                                    src1, dst1, src2, dst2, A3);

    // 12-15. Stage 3 (score+rank+MLP in ONE 32-block kernel)
    ygemm_mfma<384><<<dim3(8, NDT), 256, 0, stream>>>(A3, Bt3, Ybuf, bias3, h3);
    contract_edges<<<E_TOT / 8, 256, 0, stream>>>(Ybuf, eattr, src2, dst2, h3);
    bn_stats_k<<<256, 256, 0, stream>>>(h3, 1024, stats + 512, stats + 640);
    fused_pool_final<<<NB, 256, 0, stream>>>(h3, stats + 512, stats + 640, 1024.0f,
                                             gamma3, beta3, pw3,
                                             lin1_w, lin1_b, lin2_w, lin2_b,
                                             (float*)d_out);
}